// Round 14
// baseline (115.546 us; speedup 1.0000x reference)
//
#include <hip/hip_runtime.h>
#include <hip/hip_bf16.h>

typedef unsigned short u16;
typedef unsigned int u32;
typedef __bf16 bf16x8 __attribute__((ext_vector_type(8)));
typedef float f32x4 __attribute__((ext_vector_type(4)));
typedef u32 u32x4 __attribute__((ext_vector_type(4)));

#define MFMA16(a, b, c) __builtin_amdgcn_mfma_f32_16x16x32_bf16((a), (b), (c), 0, 0, 0)

static __device__ __forceinline__ u16 f2bf(float f) {
  __hip_bfloat16 h = __float2bfloat16(f);
  return __builtin_bit_cast(u16, h);
}

static __device__ __forceinline__ u32 pack2(float a, float b) {
  return (u32)f2bf(a) | ((u32)f2bf(b) << 16);
}

static __device__ __forceinline__ bf16x8 ldbf8(const void* p) {
  return *reinterpret_cast<const bf16x8*>(p);
}

static __device__ __forceinline__ void gload_lds16(const void* g, void* l) {
  __builtin_amdgcn_global_load_lds(
      (const __attribute__((address_space(1))) u32*)g,
      (__attribute__((address_space(3))) u32*)l, 16, 0, 0);
}

// ---------------------------------------------------------------- cvt f32->bf16 (fused x, W_qkv, W_o)
__global__ void cvt_all(const float* __restrict__ x, const float* __restrict__ wq,
                        const float* __restrict__ wo, u16* __restrict__ xb,
                        u16* __restrict__ wqb, u16* __restrict__ wob) {
  int i = blockIdx.x * 256 + threadIdx.x;  // grid 4096 -> 1,048,576 threads
  const float* s;
  u16* d;
  int j;
  if (i < 524288) {
    s = x; d = xb; j = i;
  } else if (i < 917504) {
    s = wq; d = wqb; j = i - 524288;
  } else {
    s = wo; d = wob; j = i - 917504;
  }
  const float4* p = reinterpret_cast<const float4*>(s) + (size_t)j * 2;
  float4 a = p[0], b = p[1];
  uint4 o;
  o.x = (u32)f2bf(a.x) | ((u32)f2bf(a.y) << 16);
  o.y = (u32)f2bf(a.z) | ((u32)f2bf(a.w) << 16);
  o.z = (u32)f2bf(b.x) | ((u32)f2bf(b.y) << 16);
  o.w = (u32)f2bf(b.z) | ((u32)f2bf(b.w) << 16);
  reinterpret_cast<uint4*>(d)[j] = o;
}

// ---------------------------------------------------------------- GEMM C = A*B^T + bias
// 128x128 tile, BK=64, 4 waves; 3 blocks/CU; XCD-chunked block remap.
template <bool BF16OUT>
__global__ __launch_bounds__(256, 3) void gemm_bt(const u16* __restrict__ A,
                                                  const u16* __restrict__ Bm,
                                                  const float* __restrict__ bias,
                                                  void* __restrict__ Cp,
                                                  int M, int N, int K) {
  __shared__ __align__(16) char As[128 * 64 * 2];
  __shared__ __align__(16) char Bs[128 * 64 * 2];
  const int tid = threadIdx.x;
  const int lane = tid & 63;
  const int wid = tid >> 6;
  const int fr = lane & 15, fg = lane >> 4;
  // XCD-aware bijective remap (nwg % 8 == 0 for both call sites)
  const int gx = gridDim.x, nwg = gx * gridDim.y;
  const int id = blockIdx.y * gx + blockIdx.x;
  const int nid = (id & 7) * (nwg >> 3) + (id >> 3);
  const int bm = nid / gx, bn = nid % gx;
  const int wm = (wid >> 1) * 64, wn = (wid & 1) * 64;

  f32x4 acc[4][4];
#pragma unroll
  for (int i = 0; i < 4; ++i)
#pragma unroll
    for (int j = 0; j < 4; ++j) acc[i][j] = (f32x4){0.f, 0.f, 0.f, 0.f};

  const int nk = K >> 6;
  for (int kt = 0; kt < nk; ++kt) {
#pragma unroll
    for (int it = 0; it < 4; ++it) {
      int q = it * 256 + tid;
      int row = q >> 3;
      int c = (q & 7) ^ (row & 7);  // pre-swizzled source chunk
      gload_lds16(A + (size_t)(bm * 128 + row) * K + kt * 64 + c * 8, As + q * 16);
      gload_lds16(Bm + (size_t)(bn * 128 + row) * K + kt * 64 + c * 8, Bs + q * 16);
    }
    __syncthreads();
#pragma unroll
    for (int mk = 0; mk < 2; ++mk) {
      bf16x8 af[4], bfr[4];
#pragma unroll
      for (int i = 0; i < 4; ++i) {
        int row = wm + i * 16 + fr;
        af[i] = ldbf8(As + ((row * 128 + mk * 64 + fg * 16) ^ ((row & 7) << 4)));
      }
#pragma unroll
      for (int j = 0; j < 4; ++j) {
        int row = wn + j * 16 + fr;
        bfr[j] = ldbf8(Bs + ((row * 128 + mk * 64 + fg * 16) ^ ((row & 7) << 4)));
      }
#pragma unroll
      for (int i = 0; i < 4; ++i)
#pragma unroll
        for (int j = 0; j < 4; ++j) acc[i][j] = MFMA16(af[i], bfr[j], acc[i][j]);
    }
    __syncthreads();
  }

#pragma unroll
  for (int j = 0; j < 4; ++j) {
    int col = bn * 128 + wn + j * 16 + fr;
    float bv = bias[col];
#pragma unroll
    for (int i = 0; i < 4; ++i) {
#pragma unroll
      for (int r = 0; r < 4; ++r) {
        int row = bm * 128 + wm + i * 16 + fg * 4 + r;
        float v = acc[i][j][r] + bv;
        if (BF16OUT)
          ((u16*)Cp)[(size_t)row * N + col] = f2bf(v);
        else
          ((float*)Cp)[(size_t)row * N + col] = v;
      }
    }
  }
}

// ---------------------------------------------------------------- flash attention v12
// R13 structure (128-key dbuf tiles, stage-overlap, XCD remap, no-max exp2
// softmax, l-via-MFMA, opaque hoisting, lgkm-only barriers, setprio) resharded
// to 4 waves x 64 q-rows (qs=4): each K/V ds_read_b128 feeds 4 q-subtiles ->
// LDS read volume per unit work halves vs qs=2. Grid 256 (1 block/CU,
// 1 wave/SIMD); launch_bounds(256,1) unlocks the 512-VGPR budget.
__global__ __launch_bounds__(256, 1) void attn_fwd(const u16* __restrict__ qkv,
                                                   u16* __restrict__ aout) {
  // bijective remap: 256 blocks; xcd gets 4 consecutive heads (2MB K/V in L2)
  const int id = blockIdx.y * gridDim.x + blockIdx.x;  // 0..255
  const int xcd = id & 7, slot = id >> 3;              // slot 0..31
  const int bh = xcd * 4 + (slot >> 3);
  const int qt = slot & 7;
  const int b = bh >> 4, h = bh & 15;
  const int tid = threadIdx.x, lane = tid & 63, wid = tid >> 6;
  const int fr = lane & 15, fg = (lane >> 4) & 3;

  __shared__ __align__(16) char Ks[2][2][64 * 128];   // [buf][sub] swizzled [key][d]
  __shared__ __align__(16) char VTs[2][2][64 * 128];  // [buf][sub] swizzled [d][lkey]

  const int q0 = qt * 256 + wid * 64;  // 64 q-rows per wave
  const size_t bS = (size_t)b * 2048;
  const u16* kbase = qkv + bS * 3072 + h * 192 + 64;
  const u16* vbase = qkv + bS * 3072 + h * 192 + 128;

  // ---- staging geometry (loop-invariant); 256 threads cover 64x64 K + V ----
  const int krow0 = tid >> 3, krow1 = 32 + (tid >> 3);  // 2 K rows / thread / sub
  const int kcol = (tid & 7) * 8;
  int kw0 = (krow0 * 128 + (tid & 7) * 16) ^ ((krow0 & 7) << 4);
  int kw1 = (krow1 * 128 + (tid & 7) * 16) ^ ((krow1 & 7) << 4);
  asm volatile("" : "+v"(kw0), "+v"(kw1));
  // V: key-pair + 8-d chunk per thread; logical-permuted slot vl0
  const int vs2 = (tid >> 3) * 2;  // even physical key
  const int vdc = (tid & 7) * 8;   // 8-elem dim chunk
  const int vm_ = vs2 >> 5, vG = (vs2 >> 2) & 3;
  const int vu = ((vs2 >> 4) & 1) * 2 + ((vs2 >> 1) & 1);
  const int vl0 = vm_ * 32 + ((vG ^ vu) << 3) + vu * 2;  // logical slot (even)
  int wof[8];
#pragma unroll
  for (int j = 0; j < 8; ++j) {
    int d = vdc + j;
    wof[j] = ((d * 128 + vl0 * 2) ^ ((((d & 7) ^ ((d >> 3) & 7))) << 4));
    asm volatile("" : "+v"(wof[j]));
  }
  // ---- compute-side LDS read offsets (loop-invariant, opaque) ----
  // K read: mk*64 INSIDE the XOR (mask covers bit 6); t*2048 safe outside.
  int kro[2];
#pragma unroll
  for (int mk = 0; mk < 2; ++mk) {
    kro[mk] = ((fr * 128 + mk * 64 + fg * 16) ^ ((fr & 7) << 4));
    asm volatile("" : "+v"(kro[mk]));
  }
  int vadr[4][2];
#pragma unroll
  for (int tp = 0; tp < 4; ++tp)
#pragma unroll
    for (int mk = 0; mk < 2; ++mk) {
      int d = tp * 16 + fr;
      int swz = (((d & 7) ^ ((d >> 3) & 7)) << 4);
      vadr[tp][mk] = ((d * 128 + mk * 64 + fg * 16) ^ swz);
      asm volatile("" : "+v"(vadr[tp][mk]));
    }

  // Q fragments (4 q-subtiles), pre-scaled by (1/8)*log2(e) [exp2 domain]
  bf16x8 qf[4][2];
#pragma unroll
  for (int qs = 0; qs < 4; ++qs)
#pragma unroll
    for (int mk = 0; mk < 2; ++mk) {
      bf16x8 v =
          ldbf8(qkv + (bS + q0 + qs * 16 + fr) * 3072 + h * 192 + mk * 32 + fg * 8);
#pragma unroll
      for (int e = 0; e < 8; ++e) v[e] = (__bf16)((float)v[e] * 0.1803368801f);
      qf[qs][mk] = v;
    }

  // ones B-fragment for the l row-sum MFMA
  const u32 one2 = 0x3F803F80u;
  const u32x4 onev = {one2, one2, one2, one2};
  const bf16x8 onesf = __builtin_bit_cast(bf16x8, onev);
  // opaque zero C-operand for QK MFMA
  float zs = 0.f;
  asm volatile("" : "+v"(zs));
  const f32x4 zacc = {zs, zs, zs, zs};

  f32x4 oacc[4][4];  // [qs][tp] : O[q][d=tp*16+fr]
  f32x4 lacc[4];     // [qs]
#pragma unroll
  for (int qs = 0; qs < 4; ++qs) {
#pragma unroll
    for (int t = 0; t < 4; ++t) oacc[qs][t] = (f32x4){0.f, 0.f, 0.f, 0.f};
    lacc[qs] = (f32x4){0.f, 0.f, 0.f, 0.f};
  }

// load one 128-key tile (two 64-subs) into 8 regs
#define LOADT(S0, K0, K1, K2, K3, V0, V1, V2, V3)                                         \
  K0 = *reinterpret_cast<const uint4*>(kbase + (size_t)((S0) + krow0) * 3072 + kcol);      \
  K1 = *reinterpret_cast<const uint4*>(kbase + (size_t)((S0) + krow1) * 3072 + kcol);      \
  K2 = *reinterpret_cast<const uint4*>(kbase + (size_t)((S0) + 64 + krow0) * 3072 + kcol); \
  K3 = *reinterpret_cast<const uint4*>(kbase + (size_t)((S0) + 64 + krow1) * 3072 + kcol); \
  V0 = *reinterpret_cast<const uint4*>(vbase + (size_t)((S0) + vs2) * 3072 + vdc);         \
  V1 = *reinterpret_cast<const uint4*>(vbase + (size_t)((S0) + vs2 + 1) * 3072 + vdc);     \
  V2 = *reinterpret_cast<const uint4*>(vbase + (size_t)((S0) + 64 + vs2) * 3072 + vdc);    \
  V3 = *reinterpret_cast<const uint4*>(vbase + (size_t)((S0) + 64 + vs2 + 1) * 3072 + vdc);

#define STAGEV1(VTP, V0, V1)                           \
  {                                                    \
    const u16* e0 = reinterpret_cast<const u16*>(&V0); \
    const u16* e1 = reinterpret_cast<const u16*>(&V1); \
    _Pragma("unroll") for (int j = 0; j < 8; ++j) {    \
      u32 w = (u32)e0[j] | ((u32)e1[j] << 16);         \
      *reinterpret_cast<u32*>((VTP) + wof[j]) = w;     \
    }                                                  \
  }

#define STAGE(BUF, K0, K1, K2, K3, V0, V1, V2, V3)        \
  {                                                       \
    *reinterpret_cast<uint4*>(Ks[BUF][0] + kw0) = K0;     \
    *reinterpret_cast<uint4*>(Ks[BUF][0] + kw1) = K1;     \
    *reinterpret_cast<uint4*>(Ks[BUF][1] + kw0) = K2;     \
    *reinterpret_cast<uint4*>(Ks[BUF][1] + kw1) = K3;     \
    STAGEV1(VTs[BUF][0], V0, V1);                         \
    STAGEV1(VTs[BUF][1], V2, V3);                         \
  }

// raw barrier: drain LDS ops only; global prefetch loads stay in flight
#define BAR()                                          \
  {                                                    \
    __builtin_amdgcn_sched_barrier(0);                 \
    asm volatile("s_waitcnt lgkmcnt(0)" ::: "memory"); \
    __builtin_amdgcn_s_barrier();                      \
    __builtin_amdgcn_sched_barrier(0);                 \
  }

// one 64-key sub-tile of compute, 4 q-subtiles per wave
#define COMPUTE1(KSP, VTP)                                                     \
  {                                                                            \
    f32x4 sc[4][4];                                                            \
    __builtin_amdgcn_s_setprio(1);                                             \
    _Pragma("unroll") for (int t = 0; t < 4; ++t) {                            \
      bf16x8 kf0 = ldbf8((KSP) + kro[0] + t * 2048);                           \
      bf16x8 kf1 = ldbf8((KSP) + kro[1] + t * 2048);                           \
      _Pragma("unroll") for (int qs = 0; qs < 4; ++qs) {                       \
        sc[qs][t] = MFMA16(kf0, qf[qs][0], zacc);                              \
        sc[qs][t] = MFMA16(kf1, qf[qs][1], sc[qs][t]);                         \
      }                                                                        \
    }                                                                          \
    __builtin_amdgcn_s_setprio(0);                                             \
    u32 Wp[4][2][4];                                                           \
    _Pragma("unroll") for (int qs = 0; qs < 4; ++qs)                           \
        _Pragma("unroll") for (int t = 0; t < 4; ++t) {                        \
      Wp[qs][0][t] = pack2(__builtin_amdgcn_exp2f(sc[qs][t][0]),               \
                           __builtin_amdgcn_exp2f(sc[qs][t][1]));              \
      Wp[qs][1][t] = pack2(__builtin_amdgcn_exp2f(sc[qs][t][2]),               \
                           __builtin_amdgcn_exp2f(sc[qs][t][3]));              \
    }                                                                          \
    _Pragma("unroll") for (int mk = 0; mk < 2; ++mk) {                         \
      bf16x8 pa[4];                                                            \
      _Pragma("unroll") for (int qs = 0; qs < 4; ++qs) {                       \
        u32x4 pk;                                                              \
        pk.x = Wp[qs][0][2 * mk];                                              \
        pk.y = (u32)__shfl_xor((int)Wp[qs][1][2 * mk], 16);                    \
        pk.z = (u32)__shfl_xor((int)Wp[qs][0][2 * mk + 1], 32);                \
        pk.w = (u32)__shfl_xor((int)Wp[qs][1][2 * mk + 1], 48);                \
        pa[qs] = __builtin_bit_cast(bf16x8, pk);                               \
      }                                                                        \
      __builtin_amdgcn_s_setprio(1);                                           \
      _Pragma("unroll") for (int qs = 0; qs < 4; ++qs) lacc[qs] =              \
          MFMA16(pa[qs], onesf, lacc[qs]);                                     \
      _Pragma("unroll") for (int tp = 0; tp < 4; ++tp) {                       \
        bf16x8 vf = ldbf8((VTP) + vadr[tp][mk]);                               \
        _Pragma("unroll") for (int qs = 0; qs < 4; ++qs) oacc[qs][tp] =        \
            MFMA16(pa[qs], vf, oacc[qs][tp]);                                  \
      }                                                                        \
      __builtin_amdgcn_s_setprio(0);                                           \
    }                                                                          \
  }

#define COMPUTE(BUF)                   \
  {                                    \
    COMPUTE1(Ks[BUF][0], VTs[BUF][0]); \
    COMPUTE1(Ks[BUF][1], VTs[BUF][1]); \
  }

  uint4 ka0, ka1, ka2, ka3, va0, va1, va2, va3;
  uint4 kb0, kb1, kb2, kb3, vb0, vb1, vb2, vb3;
  // prologue: tile0 -> A -> buf0; tile1 -> B; buf0 ready after BAR
  LOADT(0, ka0, ka1, ka2, ka3, va0, va1, va2, va3);
  STAGE(0, ka0, ka1, ka2, ka3, va0, va1, va2, va3);
  LOADT(128, kb0, kb1, kb2, kb3, vb0, vb1, vb2, vb3);
  BAR();
  for (int kv = 0; kv < 16; kv += 2) {
    // phase A: prefetch kv+2 -> A; stage tile kv+1 (B) -> buf1; compute tile kv (buf0)
    {
      int s0n = (kv + 2 < 16) ? (kv + 2) * 128 : 0;  // tail: harmless reload
      LOADT(s0n, ka0, ka1, ka2, ka3, va0, va1, va2, va3);
    }
    STAGE(1, kb0, kb1, kb2, kb3, vb0, vb1, vb2, vb3);
    COMPUTE(0);
    BAR();
    // phase B: prefetch kv+3 -> B; stage tile kv+2 (A) -> buf0; compute tile kv+1 (buf1)
    {
      int s0n = (kv + 3 < 16) ? (kv + 3) * 128 : 128;  // tail: harmless reload
      LOADT(s0n, kb0, kb1, kb2, kb3, vb0, vb1, vb2, vb3);
    }
    STAGE(0, ka0, ka1, ka2, ka3, va0, va1, va2, va3);
    COMPUTE(1);
    BAR();
  }
#undef LOADT
#undef STAGEV1
#undef STAGE
#undef BAR
#undef COMPUTE1
#undef COMPUTE

  // ---- epilogue: out[b, q, h*64+d] = O / l ----
#pragma unroll
  for (int qs = 0; qs < 4; ++qs) {
    float invb[4];
#pragma unroll
    for (int r = 0; r < 4; ++r) invb[r] = 1.f / lacc[qs][r];
#pragma unroll
    for (int tp = 0; tp < 4; ++tp) {
#pragma unroll
      for (int r = 0; r < 4; ++r) {
        int row = q0 + qs * 16 + fg * 4 + r;
        aout[(bS + row) * 1024 + h * 64 + tp * 16 + fr] =
            f2bf(oacc[qs][tp][r] * invb[r]);
      }
    }
  }
}

// ---------------------------------------------------------------- launch
extern "C" void kernel_launch(void* const* d_in, const int* in_sizes, int n_in,
                              void* d_out, int out_size, void* d_ws, size_t ws_size,
                              hipStream_t stream) {
  const float* x = (const float*)d_in[0];
  const float* Wqkv = (const float*)d_in[1];
  const float* bqkv = (const float*)d_in[2];
  const float* Wo = (const float*)d_in[3];
  const float* bo = (const float*)d_in[4];
  float* out = (float*)d_out;
  char* ws = (char*)d_ws;

  u16* xb = (u16*)(ws);                       //  8,388,608  x bf16 [4096,1024]
  u16* wqb = (u16*)(ws + 8388608);            //  6,291,456  W_qkv bf16 [3072,1024]
  u16* wob = (u16*)(ws + 14680064);           //  2,097,152  W_o bf16 [1024,1024]
  u16* qkvb = (u16*)(ws + 16777216);          // 25,165,824  qkv bf16 [4096,3072]
  u16* attb = (u16*)(ws + 41943040);          //  8,388,608  attn out bf16 [4096,1024]

  cvt_all<<<4096, 256, 0, stream>>>(x, Wqkv, Wo, xb, wqb, wob);

  gemm_bt<true><<<dim3(24, 32), 256, 0, stream>>>(xb, wqb, bqkv, qkvb, 4096, 3072, 1024);
  attn_fwd<<<dim3(8, 32), 256, 0, stream>>>(qkvb, attb);
  gemm_bt<false><<<dim3(8, 32), 256, 0, stream>>>(attb, wob, bo, out, 4096, 1024, 1024);
}

// Round 18
// 106.327 us; speedup vs baseline: 1.0867x; 1.0867x over previous
//
#include <hip/hip_runtime.h>
#include <hip/hip_bf16.h>

typedef unsigned short u16;
typedef unsigned int u32;
typedef __bf16 bf16x8 __attribute__((ext_vector_type(8)));
typedef float f32x4 __attribute__((ext_vector_type(4)));
typedef u32 u32x4 __attribute__((ext_vector_type(4)));

#define MFMA16(a, b, c) __builtin_amdgcn_mfma_f32_16x16x32_bf16((a), (b), (c), 0, 0, 0)

static __device__ __forceinline__ u16 f2bf(float f) {
  __hip_bfloat16 h = __float2bfloat16(f);
  return __builtin_bit_cast(u16, h);
}

static __device__ __forceinline__ u32 pack2(float a, float b) {
  return (u32)f2bf(a) | ((u32)f2bf(b) << 16);
}

static __device__ __forceinline__ bf16x8 ldbf8(const void* p) {
  return *reinterpret_cast<const bf16x8*>(p);
}

static __device__ __forceinline__ void gload_lds16(const void* g, void* l) {
  __builtin_amdgcn_global_load_lds(
      (const __attribute__((address_space(1))) u32*)g,
      (__attribute__((address_space(3))) u32*)l, 16, 0, 0);
}

// ---------------------------------------------------------------- cvt f32->bf16 (fused x, W_qkv, W_o)
__global__ void cvt_all(const float* __restrict__ x, const float* __restrict__ wq,
                        const float* __restrict__ wo, u16* __restrict__ xb,
                        u16* __restrict__ wqb, u16* __restrict__ wob) {
  int i = blockIdx.x * 256 + threadIdx.x;  // grid 4096 -> 1,048,576 threads
  const float* s;
  u16* d;
  int j;
  if (i < 524288) {
    s = x; d = xb; j = i;
  } else if (i < 917504) {
    s = wq; d = wqb; j = i - 524288;
  } else {
    s = wo; d = wob; j = i - 917504;
  }
  const float4* p = reinterpret_cast<const float4*>(s) + (size_t)j * 2;
  float4 a = p[0], b = p[1];
  uint4 o;
  o.x = (u32)f2bf(a.x) | ((u32)f2bf(a.y) << 16);
  o.y = (u32)f2bf(a.z) | ((u32)f2bf(a.w) << 16);
  o.z = (u32)f2bf(b.x) | ((u32)f2bf(b.y) << 16);
  o.w = (u32)f2bf(b.z) | ((u32)f2bf(b.w) << 16);
  reinterpret_cast<uint4*>(d)[j] = o;
}

// ---------------------------------------------------------------- GEMM C = A*B^T + bias
// 128x128 tile, BK=64, 4 waves; 3 blocks/CU; XCD-chunked block remap.
template <bool BF16OUT>
__global__ __launch_bounds__(256, 3) void gemm_bt(const u16* __restrict__ A,
                                                  const u16* __restrict__ Bm,
                                                  const float* __restrict__ bias,
                                                  void* __restrict__ Cp,
                                                  int M, int N, int K) {
  __shared__ __align__(16) char As[128 * 64 * 2];
  __shared__ __align__(16) char Bs[128 * 64 * 2];
  const int tid = threadIdx.x;
  const int lane = tid & 63;
  const int wid = tid >> 6;
  const int fr = lane & 15, fg = lane >> 4;
  // XCD-aware bijective remap (nwg % 8 == 0 for both call sites)
  const int gx = gridDim.x, nwg = gx * gridDim.y;
  const int id = blockIdx.y * gx + blockIdx.x;
  const int nid = (id & 7) * (nwg >> 3) + (id >> 3);
  const int bm = nid / gx, bn = nid % gx;
  const int wm = (wid >> 1) * 64, wn = (wid & 1) * 64;

  f32x4 acc[4][4];
#pragma unroll
  for (int i = 0; i < 4; ++i)
#pragma unroll
    for (int j = 0; j < 4; ++j) acc[i][j] = (f32x4){0.f, 0.f, 0.f, 0.f};

  const int nk = K >> 6;
  for (int kt = 0; kt < nk; ++kt) {
#pragma unroll
    for (int it = 0; it < 4; ++it) {
      int q = it * 256 + tid;
      int row = q >> 3;
      int c = (q & 7) ^ (row & 7);  // pre-swizzled source chunk
      gload_lds16(A + (size_t)(bm * 128 + row) * K + kt * 64 + c * 8, As + q * 16);
      gload_lds16(Bm + (size_t)(bn * 128 + row) * K + kt * 64 + c * 8, Bs + q * 16);
    }
    __syncthreads();
#pragma unroll
    for (int mk = 0; mk < 2; ++mk) {
      bf16x8 af[4], bfr[4];
#pragma unroll
      for (int i = 0; i < 4; ++i) {
        int row = wm + i * 16 + fr;
        af[i] = ldbf8(As + ((row * 128 + mk * 64 + fg * 16) ^ ((row & 7) << 4)));
      }
#pragma unroll
      for (int j = 0; j < 4; ++j) {
        int row = wn + j * 16 + fr;
        bfr[j] = ldbf8(Bs + ((row * 128 + mk * 64 + fg * 16) ^ ((row & 7) << 4)));
      }
#pragma unroll
      for (int i = 0; i < 4; ++i)
#pragma unroll
        for (int j = 0; j < 4; ++j) acc[i][j] = MFMA16(af[i], bfr[j], acc[i][j]);
    }
    __syncthreads();
  }

#pragma unroll
  for (int j = 0; j < 4; ++j) {
    int col = bn * 128 + wn + j * 16 + fr;
    float bv = bias[col];
#pragma unroll
    for (int i = 0; i < 4; ++i) {
#pragma unroll
      for (int r = 0; r < 4; ++r) {
        int row = bm * 128 + wm + i * 16 + fg * 4 + r;
        float v = acc[i][j][r] + bv;
        if (BF16OUT)
          ((u16*)Cp)[(size_t)row * N + col] = f2bf(v);
        else
          ((float*)Cp)[(size_t)row * N + col] = v;
      }
    }
  }
}

// ---------------------------------------------------------------- flash attention v13
// R13 structure (4 waves x 32 q-rows, 128-key dbuf tiles, stage-overlap, XCD
// remap, no-max exp2 softmax, l-via-MFMA, opaque hoisting, lgkm-only barriers,
// setprio) + SHUFFLE-FREE PV: V's logical key order is re-chosen as
//   phys s = 32m+16u+4g+e  ->  logical L = 32m+8g+4u+e
// so each lane's OWN sc values are exactly its PV A-fragment (swapped-QK gives
// lane (fr,fg) the keys k=16t+4fg+reg; A-frag slot fg*8+j now maps to those).
// Deletes 12 ds_bpermute + 2 serial lgkm waits per wave per 64-key subtile.
__global__ __launch_bounds__(256, 2) void attn_fwd(const u16* __restrict__ qkv,
                                                   u16* __restrict__ aout) {
  // bijective remap: id = slot*8 + xcd; bh = xcd*4 + (slot>>4); qt = slot&15
  const int id = blockIdx.y * gridDim.x + blockIdx.x;  // 0..511
  const int xcd = id & 7, slot = id >> 3;
  const int bh = xcd * 4 + (slot >> 4);
  const int qt = slot & 15;
  const int b = bh >> 4, h = bh & 15;
  const int tid = threadIdx.x, lane = tid & 63, wid = tid >> 6;
  const int fr = lane & 15, fg = (lane >> 4) & 3;

  __shared__ __align__(16) char Ks[2][2][64 * 128];   // [buf][sub] swizzled [key][d]
  __shared__ __align__(16) char VTs[2][2][64 * 128];  // [buf][sub] swizzled [d][lkey]

  const int q0 = qt * 128 + wid * 32;  // 32 q-rows per wave
  const size_t bS = (size_t)b * 2048;
  const u16* kbase = qkv + bS * 3072 + h * 192 + 64;
  const u16* vbase = qkv + bS * 3072 + h * 192 + 128;

  // ---- staging geometry (loop-invariant); 256 threads cover 64x64 K + V ----
  const int krow0 = tid >> 3, krow1 = 32 + (tid >> 3);  // 2 K rows / thread / sub
  const int kcol = (tid & 7) * 8;
  int kw0 = (krow0 * 128 + (tid & 7) * 16) ^ ((krow0 & 7) << 4);
  int kw1 = (krow1 * 128 + (tid & 7) * 16) ^ ((krow1 & 7) << 4);
  asm volatile("" : "+v"(kw0), "+v"(kw1));
  // V: key-pair + 8-d chunk per thread; shuffle-free logical slot:
  //   phys s = 32m+16u+4g+e -> L = 32m+8g+4u+e  (pairs stay adjacent: e even)
  const int vs2 = (tid >> 3) * 2;  // even physical key
  const int vdc = (tid & 7) * 8;   // 8-elem dim chunk
  const int vl0 = 32 * (vs2 >> 5) + 8 * ((vs2 >> 2) & 3) + 4 * ((vs2 >> 4) & 1) +
                  (vs2 & 3);  // logical slot (even)
  int wof[8];
#pragma unroll
  for (int j = 0; j < 8; ++j) {
    int d = vdc + j;
    wof[j] = ((d * 128 + vl0 * 2) ^ ((((d & 7) ^ ((d >> 3) & 7))) << 4));
    asm volatile("" : "+v"(wof[j]));
  }
  // ---- compute-side LDS read offsets (loop-invariant, opaque) ----
  // K read: mk*64 INSIDE the XOR (mask covers bit 6); t*2048 safe outside.
  int kro[2];
#pragma unroll
  for (int mk = 0; mk < 2; ++mk) {
    kro[mk] = ((fr * 128 + mk * 64 + fg * 16) ^ ((fr & 7) << 4));
    asm volatile("" : "+v"(kro[mk]));
  }
  int vadr[4][2];
#pragma unroll
  for (int tp = 0; tp < 4; ++tp)
#pragma unroll
    for (int mk = 0; mk < 2; ++mk) {
      int d = tp * 16 + fr;
      int swz = (((d & 7) ^ ((d >> 3) & 7)) << 4);
      vadr[tp][mk] = ((d * 128 + mk * 64 + fg * 16) ^ swz);
      asm volatile("" : "+v"(vadr[tp][mk]));
    }

  // Q fragments (2 q-subtiles), pre-scaled by (1/8)*log2(e) [exp2 domain]
  bf16x8 qf[2][2];
#pragma unroll
  for (int qs = 0; qs < 2; ++qs)
#pragma unroll
    for (int mk = 0; mk < 2; ++mk) {
      bf16x8 v =
          ldbf8(qkv + (bS + q0 + qs * 16 + fr) * 3072 + h * 192 + mk * 32 + fg * 8);
#pragma unroll
      for (int e = 0; e < 8; ++e) v[e] = (__bf16)((float)v[e] * 0.1803368801f);
      qf[qs][mk] = v;
    }

  // ones B-fragment for the l row-sum MFMA (k-permutation invariant)
  const u32 one2 = 0x3F803F80u;
  const u32x4 onev = {one2, one2, one2, one2};
  const bf16x8 onesf = __builtin_bit_cast(bf16x8, onev);
  // opaque zero C-operand for QK MFMA
  float zs = 0.f;
  asm volatile("" : "+v"(zs));
  const f32x4 zacc = {zs, zs, zs, zs};

  f32x4 oacc0[4], oacc1[4];  // [tp] : O[q][d=tp*16+fr] for qs=0,1
#pragma unroll
  for (int t = 0; t < 4; ++t) {
    oacc0[t] = (f32x4){0.f, 0.f, 0.f, 0.f};
    oacc1[t] = (f32x4){0.f, 0.f, 0.f, 0.f};
  }
  f32x4 lacc0 = (f32x4){0.f, 0.f, 0.f, 0.f};
  f32x4 lacc1 = (f32x4){0.f, 0.f, 0.f, 0.f};

// load one 128-key tile (two 64-subs) into 8 regs
#define LOADT(S0, K0, K1, K2, K3, V0, V1, V2, V3)                                         \
  K0 = *reinterpret_cast<const uint4*>(kbase + (size_t)((S0) + krow0) * 3072 + kcol);      \
  K1 = *reinterpret_cast<const uint4*>(kbase + (size_t)((S0) + krow1) * 3072 + kcol);      \
  K2 = *reinterpret_cast<const uint4*>(kbase + (size_t)((S0) + 64 + krow0) * 3072 + kcol); \
  K3 = *reinterpret_cast<const uint4*>(kbase + (size_t)((S0) + 64 + krow1) * 3072 + kcol); \
  V0 = *reinterpret_cast<const uint4*>(vbase + (size_t)((S0) + vs2) * 3072 + vdc);         \
  V1 = *reinterpret_cast<const uint4*>(vbase + (size_t)((S0) + vs2 + 1) * 3072 + vdc);     \
  V2 = *reinterpret_cast<const uint4*>(vbase + (size_t)((S0) + 64 + vs2) * 3072 + vdc);    \
  V3 = *reinterpret_cast<const uint4*>(vbase + (size_t)((S0) + 64 + vs2 + 1) * 3072 + vdc);

#define STAGEV1(VTP, V0, V1)                           \
  {                                                    \
    const u16* e0 = reinterpret_cast<const u16*>(&V0); \
    const u16* e1 = reinterpret_cast<const u16*>(&V1); \
    _Pragma("unroll") for (int j = 0; j < 8; ++j) {    \
      u32 w = (u32)e0[j] | ((u32)e1[j] << 16);         \
      *reinterpret_cast<u32*>((VTP) + wof[j]) = w;     \
    }                                                  \
  }

#define STAGE(BUF, K0, K1, K2, K3, V0, V1, V2, V3)        \
  {                                                       \
    *reinterpret_cast<uint4*>(Ks[BUF][0] + kw0) = K0;     \
    *reinterpret_cast<uint4*>(Ks[BUF][0] + kw1) = K1;     \
    *reinterpret_cast<uint4*>(Ks[BUF][1] + kw0) = K2;     \
    *reinterpret_cast<uint4*>(Ks[BUF][1] + kw1) = K3;     \
    STAGEV1(VTs[BUF][0], V0, V1);                         \
    STAGEV1(VTs[BUF][1], V2, V3);                         \
  }

// raw barrier: drain LDS ops only; global prefetch loads stay in flight
#define BAR()                                          \
  {                                                    \
    __builtin_amdgcn_sched_barrier(0);                 \
    asm volatile("s_waitcnt lgkmcnt(0)" ::: "memory"); \
    __builtin_amdgcn_s_barrier();                      \
    __builtin_amdgcn_sched_barrier(0);                 \
  }

// one 64-key sub-tile of compute; PV A-frags are lane-local (no shuffles)
#define COMPUTE1(KSP, VTP)                                                     \
  {                                                                            \
    f32x4 sc0[4], sc1[4];                                                      \
    __builtin_amdgcn_s_setprio(1);                                             \
    _Pragma("unroll") for (int t = 0; t < 4; ++t) {                            \
      bf16x8 kf0 = ldbf8((KSP) + kro[0] + t * 2048);                           \
      bf16x8 kf1 = ldbf8((KSP) + kro[1] + t * 2048);                           \
      sc0[t] = MFMA16(kf0, qf[0][0], zacc);                                    \
      sc0[t] = MFMA16(kf1, qf[0][1], sc0[t]);                                  \
      sc1[t] = MFMA16(kf0, qf[1][0], zacc);                                    \
      sc1[t] = MFMA16(kf1, qf[1][1], sc1[t]);                                  \
    }                                                                          \
    __builtin_amdgcn_s_setprio(0);                                             \
    u32 Wp0[2][4], Wp1[2][4];                                                  \
    _Pragma("unroll") for (int t = 0; t < 4; ++t) {                            \
      Wp0[0][t] = pack2(__builtin_amdgcn_exp2f(sc0[t][0]),                     \
                        __builtin_amdgcn_exp2f(sc0[t][1]));                    \
      Wp0[1][t] = pack2(__builtin_amdgcn_exp2f(sc0[t][2]),                     \
                        __builtin_amdgcn_exp2f(sc0[t][3]));                    \
      Wp1[0][t] = pack2(__builtin_amdgcn_exp2f(sc1[t][0]),                     \
                        __builtin_amdgcn_exp2f(sc1[t][1]));                    \
      Wp1[1][t] = pack2(__builtin_amdgcn_exp2f(sc1[t][2]),                     \
                        __builtin_amdgcn_exp2f(sc1[t][3]));                    \
    }                                                                          \
    _Pragma("unroll") for (int mk = 0; mk < 2; ++mk) {                         \
      u32x4 pk0, pk1;                                                          \
      pk0.x = Wp0[0][2 * mk];                                                  \
      pk0.y = Wp0[1][2 * mk];                                                  \
      pk0.z = Wp0[0][2 * mk + 1];                                              \
      pk0.w = Wp0[1][2 * mk + 1];                                              \
      pk1.x = Wp1[0][2 * mk];                                                  \
      pk1.y = Wp1[1][2 * mk];                                                  \
      pk1.z = Wp1[0][2 * mk + 1];                                              \
      pk1.w = Wp1[1][2 * mk + 1];                                              \
      bf16x8 pa0 = __builtin_bit_cast(bf16x8, pk0);                            \
      bf16x8 pa1 = __builtin_bit_cast(bf16x8, pk1);                            \
      __builtin_amdgcn_s_setprio(1);                                           \
      lacc0 = MFMA16(pa0, onesf, lacc0);                                       \
      lacc1 = MFMA16(pa1, onesf, lacc1);                                       \
      _Pragma("unroll") for (int tp = 0; tp < 4; ++tp) {                       \
        bf16x8 vf = ldbf8((VTP) + vadr[tp][mk]);                               \
        oacc0[tp] = MFMA16(pa0, vf, oacc0[tp]);                                \
        oacc1[tp] = MFMA16(pa1, vf, oacc1[tp]);                                \
      }                                                                        \
      __builtin_amdgcn_s_setprio(0);                                           \
    }                                                                          \
  }

#define COMPUTE(BUF)                   \
  {                                    \
    COMPUTE1(Ks[BUF][0], VTs[BUF][0]); \
    COMPUTE1(Ks[BUF][1], VTs[BUF][1]); \
  }

  uint4 ka0, ka1, ka2, ka3, va0, va1, va2, va3;
  uint4 kb0, kb1, kb2, kb3, vb0, vb1, vb2, vb3;
  // prologue: tile0 -> A -> buf0; tile1 -> B; buf0 ready after BAR
  LOADT(0, ka0, ka1, ka2, ka3, va0, va1, va2, va3);
  STAGE(0, ka0, ka1, ka2, ka3, va0, va1, va2, va3);
  LOADT(128, kb0, kb1, kb2, kb3, vb0, vb1, vb2, vb3);
  BAR();
  for (int kv = 0; kv < 16; kv += 2) {
    // phase A: prefetch kv+2 -> A; stage tile kv+1 (B) -> buf1; compute tile kv (buf0)
    {
      int s0n = (kv + 2 < 16) ? (kv + 2) * 128 : 0;  // tail: harmless reload
      LOADT(s0n, ka0, ka1, ka2, ka3, va0, va1, va2, va3);
    }
    STAGE(1, kb0, kb1, kb2, kb3, vb0, vb1, vb2, vb3);
    COMPUTE(0);
    BAR();
    // phase B: prefetch kv+3 -> B; stage tile kv+2 (A) -> buf0; compute tile kv+1 (buf1)
    {
      int s0n = (kv + 3 < 16) ? (kv + 3) * 128 : 128;  // tail: harmless reload
      LOADT(s0n, kb0, kb1, kb2, kb3, vb0, vb1, vb2, vb3);
    }
    STAGE(0, ka0, ka1, ka2, ka3, va0, va1, va2, va3);
    COMPUTE(1);
    BAR();
  }
#undef LOADT
#undef STAGEV1
#undef STAGE
#undef BAR
#undef COMPUTE1
#undef COMPUTE

  // ---- epilogue: out[b, q, h*64+d] = O / l ----
  {
    float invb0[4], invb1[4];
#pragma unroll
    for (int r = 0; r < 4; ++r) {
      invb0[r] = 1.f / lacc0[r];
      invb1[r] = 1.f / lacc1[r];
    }
#pragma unroll
    for (int tp = 0; tp < 4; ++tp) {
#pragma unroll
      for (int r = 0; r < 4; ++r) {
        int row0 = q0 + fg * 4 + r;
        aout[(bS + row0) * 1024 + h * 64 + tp * 16 + fr] =
            f2bf(oacc0[tp][r] * invb0[r]);
        int row1 = q0 + 16 + fg * 4 + r;
        aout[(bS + row1) * 1024 + h * 64 + tp * 16 + fr] =
            f2bf(oacc1[tp][r] * invb1[r]);
      }
    }
  }
}

// ---------------------------------------------------------------- launch
extern "C" void kernel_launch(void* const* d_in, const int* in_sizes, int n_in,
                              void* d_out, int out_size, void* d_ws, size_t ws_size,
                              hipStream_t stream) {
  const float* x = (const float*)d_in[0];
  const float* Wqkv = (const float*)d_in[1];
  const float* bqkv = (const float*)d_in[2];
  const float* Wo = (const float*)d_in[3];
  const float* bo = (const float*)d_in[4];
  float* out = (float*)d_out;
  char* ws = (char*)d_ws;

  u16* xb = (u16*)(ws);                       //  8,388,608  x bf16 [4096,1024]
  u16* wqb = (u16*)(ws + 8388608);            //  6,291,456  W_qkv bf16 [3072,1024]
  u16* wob = (u16*)(ws + 14680064);           //  2,097,152  W_o bf16 [1024,1024]
  u16* qkvb = (u16*)(ws + 16777216);          // 25,165,824  qkv bf16 [4096,3072]
  u16* attb = (u16*)(ws + 41943040);          //  8,388,608  attn out bf16 [4096,1024]

  cvt_all<<<4096, 256, 0, stream>>>(x, Wqkv, Wo, xb, wqb, wob);

  gemm_bt<true><<<dim3(24, 32), 256, 0, stream>>>(xb, wqb, bqkv, qkvb, 4096, 3072, 1024);
  attn_fwd<<<dim3(16, 32), 256, 0, stream>>>(qkvb, attb);
  gemm_bt<false><<<dim3(8, 32), 256, 0, stream>>>(attb, wob, bo, out, 4096, 1024, 1024);
}